// Round 8
// baseline (4818.410 us; speedup 1.0000x reference)
//
#include <hip/hip_runtime.h>

// ---------------- problem constants ----------------
#define NB 256     // batch
#define NT 512     // seq len
#define NI 128     // input size
#define NH 512     // hidden
#define NO 128     // output size
#define NGRP 16    // batch groups
#define RPG 16     // rows (batch) per group
#define BPG 8      // blocks per group (each owns 64 cols)

typedef __attribute__((ext_vector_type(8))) __bf16 bf16x8;
typedef __attribute__((ext_vector_type(4))) float  f32x4;
typedef unsigned long long u64;

#define MFMA16(a,b,c) __builtin_amdgcn_mfma_f32_16x16x32_bf16((a),(b),(c),0,0,0)

// ---------------- LDS layout (x, h0, h1 all double-buffered) ----------------
#define XSZ   (RPG*NI*2)            // 4096
#define HSZ   (RPG*NH*2)            // 16384
#define XOFF  0
#define H0OFF (2*XSZ)               // 8192
#define H1OFF (H0OFF + 2*HSZ)       // 40960
#define SMEM_BYTES (H1OFF + 2*HSZ)  // 73728

// ---------------- exchange: u64 data slabs + u32 checksum tags ----------------
#define SLABU   2048                // u64 per (layer,parity,group) slab = 16KB
#define DATAU   (4*NGRP*SLABU)      // 131072 u64 = 1MB
// tags: u32, same geometry, at byte offset 1MB

__device__ __forceinline__ float fast_tanh(float x){
  x = fminf(15.f, fmaxf(-15.f, x));
  float e = __expf(2.f * x);
  return 1.f - 2.f / (e + 1.f);
}

__device__ __forceinline__ bf16x8 cvt8(float4 a, float4 b){
  bf16x8 r;
  r[0]=(__bf16)a.x; r[1]=(__bf16)a.y; r[2]=(__bf16)a.z; r[3]=(__bf16)a.w;
  r[4]=(__bf16)b.x; r[5]=(__bf16)b.y; r[6]=(__bf16)b.z; r[7]=(__bf16)b.w;
  return r;
}

__device__ __forceinline__ bf16x8 loadWfrag(const float* __restrict__ W, int ldk, int row, int k0){
  const float4* p = (const float4*)(W + (size_t)row * ldk + k0);
  return cvt8(p[0], p[1]);
}

// proven medium: relaxed agent-scope atomics (coherent at L3)
__device__ __forceinline__ void st_u64(u64* p, u64 v){
  __hip_atomic_store(p, v, __ATOMIC_RELAXED, __HIP_MEMORY_SCOPE_AGENT);
}
__device__ __forceinline__ u64 ld_u64(const u64* p){
  return __hip_atomic_load(p, __ATOMIC_RELAXED, __HIP_MEMORY_SCOPE_AGENT);
}
__device__ __forceinline__ void st_u32(unsigned* p, unsigned v){
  __hip_atomic_store(p, v, __ATOMIC_RELAXED, __HIP_MEMORY_SCOPE_AGENT);
}
__device__ __forceinline__ unsigned ld_u32(const unsigned* p){
  return __hip_atomic_load(p, __ATOMIC_RELAXED, __HIP_MEMORY_SCOPE_AGENT);
}

__device__ __forceinline__ u64 pack4bf(f32x4 v){
  union { __bf16 h[4]; u64 u; } un;
  un.h[0]=(__bf16)v[0]; un.h[1]=(__bf16)v[1]; un.h[2]=(__bf16)v[2]; un.h[3]=(__bf16)v[3];
  return un.u;
}

// checksum tag: staleness + tearing detection; mismatch -> retry
__device__ __forceinline__ unsigned cksum(unsigned tick, u64 d){
  return tick + (unsigned)d + (unsigned)(d >> 32);
}

__device__ __forceinline__ u64* slabD(u64* b, int l, int p, int g){
  return b + ((size_t)(((l << 1) | p) * NGRP + g)) * SLABU;
}
__device__ __forceinline__ unsigned* slabT(unsigned* b, int l, int p, int g){
  return b + ((size_t)(((l << 1) | p) * NGRP + g)) * SLABU;
}

__global__ __launch_bounds__(256, 1)
void rnn_persistent(const float* __restrict__ x,
                    const float* __restrict__ hid,
                    const float* __restrict__ Wih0, const float* __restrict__ bih0,
                    const float* __restrict__ Whh0, const float* __restrict__ bhh0,
                    const float* __restrict__ Wih1, const float* __restrict__ bih1,
                    const float* __restrict__ Whh1, const float* __restrict__ bhh1,
                    const float* __restrict__ fcW,  const float* __restrict__ fcb,
                    float* __restrict__ out,
                    u64* __restrict__ ex)           // data; u32 tags at ex+DATAU
{
  __shared__ __align__(16) char smem[SMEM_BYTES];

  const int tid  = threadIdx.x;
  const int lane = tid & 63;
  const int wv   = tid >> 6;
  const int lr   = lane & 15;
  const int lq   = lane >> 4;

  const int bq  = blockIdx.x;
  const int j   = (bq >> 3) & 7;            // block-in-group: cols [j*64, j*64+64)
  const int g   = (bq & 7) + 8 * (bq >> 6); // group 0..15
  const int cb  = j * 64 + wv * 16;
  const int row0 = g * RPG;
  const int myq  = j * 16 + wv * 4 + lq;    // col-quad index 0..127
  const int idx  = lr * 128 + myq;          // quantum index in slab

  u64* const dat = ex;
  unsigned* const tag = (unsigned*)(ex + DATAU);

  // ---------------- weights -> registers (MFMA A operands) ----------------
  bf16x8 wih0[4], whh0[16], wih1[16], whh1[16];
#pragma unroll
  for (int kt = 0; kt < 4;  ++kt) wih0[kt] = loadWfrag(Wih0, NI, cb + lr, kt*32 + lq*8);
#pragma unroll
  for (int kt = 0; kt < 16; ++kt) whh0[kt] = loadWfrag(Whh0, NH, cb + lr, kt*32 + lq*8);
#pragma unroll
  for (int kt = 0; kt < 16; ++kt) wih1[kt] = loadWfrag(Wih1, NH, cb + lr, kt*32 + lq*8);
#pragma unroll
  for (int kt = 0; kt < 16; ++kt) whh1[kt] = loadWfrag(Whh1, NH, cb + lr, kt*32 + lq*8);

  const f32x4 bias0 = *(const f32x4*)(bih0 + cb + lq*4) + *(const f32x4*)(bhh0 + cb + lq*4);
  const f32x4 bias1 = *(const f32x4*)(bih1 + cb + lq*4) + *(const f32x4*)(bhh1 + cb + lq*4);

  // ---------------- prologue staging ----------------
  { // x_0 -> X buf0
    int r = tid >> 4, i0 = (tid & 15) * 8;
    const float4* xp = (const float4*)(x + ((size_t)(row0 + r) * NT + 0) * NI + i0);
    bf16x8 v = cvt8(xp[0], xp[1]);
    int o = r * 256 + i0 * 2;
    *(bf16x8*)(smem + XOFF + (o ^ ((r & 7) << 4))) = v;
  }
#pragma unroll
  for (int it = 0; it < 4; ++it) { // hidden[0] -> h0 buf0 ; hidden[1] -> h1 buf1
    int e = it * 2048 + tid * 8;
    int r = e >> 9, c = e & 511;
    int o = r * 1024 + c * 2;
    const float4* hp0 = (const float4*)(hid + (size_t)(row0 + r) * NH + c);
    *(bf16x8*)(smem + H0OFF + (o ^ ((r & 7) << 4))) = cvt8(hp0[0], hp0[1]);
    const float4* hp1 = (const float4*)(hid + (size_t)NB * NH + (size_t)(row0 + r) * NH + c);
    *(bf16x8*)(smem + H1OFF + HSZ + (o ^ ((r & 7) << 4))) = cvt8(hp1[0], hp1[1]);
  }
  __syncthreads();

#define HFRAG(base, kt) (*(const bf16x8*)((base) + lr * 1024 + (((kt) * 64 + lq * 16) ^ ((lr & 7) << 4))))

#define LOAD8(V, G, D, T)                                                            \
  { _Pragma("unroll") for (int i_ = 0; i_ < 8; ++i_) V[i_] = ld_u64((D) + i_*256 + tid); \
    _Pragma("unroll") for (int i_ = 0; i_ < 8; ++i_) G[i_] = ld_u32((T) + i_*256 + tid); }

#define CHECK8(OK, V, G, TICK)                                                       \
  { OK = true;                                                                       \
    _Pragma("unroll") for (int i_ = 0; i_ < 8; ++i_)                                 \
      OK &= (G[i_] == cksum((TICK), V[i_])); }

#define RESTAGE8(BASE, V)                                                            \
  { _Pragma("unroll") for (int i_ = 0; i_ < 8; ++i_) {                               \
      int o_ = (i_ * 256 + tid) * 8, r_ = o_ >> 10;                                  \
      *(u64*)((BASE) + (o_ ^ ((r_ & 7) << 4))) = V[i_]; } }

  // tick t: compute h0(t) [t<NT] and h1(t-1) [t>0]; ONE barrier per tick
  for (int t = 0; t <= NT; ++t) {
    const char* xA  = smem + XOFF  + (t & 1) * XSZ;
    const char* h0A = smem + H0OFF + (t & 1) * HSZ;
    const char* h1A = smem + H1OFF + (t & 1) * HSZ;
    char* h0N = smem + H0OFF + ((t + 1) & 1) * HSZ;
    char* h1N = smem + H1OFF + ((t + 1) & 1) * HSZ;
    const bool do0 = (t < NT), do1 = (t > 0);
    const unsigned tick = (unsigned)(t + 1);

    u64*      D0 = slabD(dat, 0, t & 1, g);
    unsigned* T0 = slabT(tag, 0, t & 1, g);
    u64*      D1 = slabD(dat, 1, (t + 1) & 1, g);
    unsigned* T1 = slabT(tag, 1, (t + 1) & 1, g);

    u64 v0[8], v1[8];
    unsigned g0[8], g1[8];

    // ---- layer 0 compute + publish ----
    if (do0) {
      f32x4 a0={0.f,0.f,0.f,0.f}, a1={0.f,0.f,0.f,0.f};
#pragma unroll
      for (int kt = 0; kt < 4; ++kt) {
        bf16x8 a = *(const bf16x8*)(xA + lr * 256 + ((kt * 64 + lq * 16) ^ ((lr & 7) << 4)));
        a0 = MFMA16(wih0[kt], a, a0);
      }
#pragma unroll
      for (int kt = 0; kt < 16; ++kt) {
        bf16x8 a = HFRAG(h0A, kt);
        if (kt & 1) a1 = MFMA16(whh0[kt], a, a1); else a0 = MFMA16(whh0[kt], a, a0);
      }
      f32x4 s = a0 + a1 + bias0;
      f32x4 h; h[0]=fast_tanh(s[0]); h[1]=fast_tanh(s[1]); h[2]=fast_tanh(s[2]); h[3]=fast_tanh(s[3]);
      if (t == NT - 1)
        *(f32x4*)(out + NB * NO + (size_t)(row0 + lr) * NH + cb + lq * 4) = h;  // new_hidden[0]
      u64 d = pack4bf(h);
      st_u64(D0 + idx, d);
      st_u32(T0 + idx, cksum(tick, d));
      // speculative h0-slab ingest: loads fly during L1 compute below
      LOAD8(v0, g0, D0, T0);
    }

    // ---- layer 1 compute + publish ----
    if (do1) {
      f32x4 c0={0.f,0.f,0.f,0.f}, c1={0.f,0.f,0.f,0.f};
#pragma unroll
      for (int kt = 0; kt < 16; ++kt) {
        bf16x8 a = HFRAG(h0A, kt);   // h0(t-1)
        if (kt & 1) c1 = MFMA16(wih1[kt], a, c1); else c0 = MFMA16(wih1[kt], a, c0);
      }
#pragma unroll
      for (int kt = 0; kt < 16; ++kt) {
        bf16x8 a = HFRAG(h1A, kt);   // h1(t-2)
        if (kt & 1) c1 = MFMA16(whh1[kt], a, c1); else c0 = MFMA16(whh1[kt], a, c0);
      }
      f32x4 s = c0 + c1 + bias1;
      f32x4 h; h[0]=fast_tanh(s[0]); h[1]=fast_tanh(s[1]); h[2]=fast_tanh(s[2]); h[3]=fast_tanh(s[3]);
      if (t == NT)
        *(f32x4*)(out + NB * NO + (size_t)NB * NH + (size_t)(row0 + lr) * NH + cb + lq * 4) = h;  // new_hidden[1]
      u64 d = pack4bf(h);
      st_u64(D1 + idx, d);
      st_u32(T1 + idx, cksum(tick, d));
      // speculative h1-slab ingest: loads fly during x-prefetch / h0 work below
      LOAD8(v1, g1, D1, T1);
    }
    if (t == NT) break;

    // x(t+1) prefetch to registers
    float4 xr0, xr1;
    const bool xpf = (t + 1 < NT);
    if (xpf) {
      int r = tid >> 4, i0 = (tid & 15) * 8;
      const float4* xp = (const float4*)(x + ((size_t)(row0 + r) * NT + (t + 1)) * NI + i0);
      xr0 = xp[0]; xr1 = xp[1];
    }

    // ---- validate h0 (speculative values first; rare retry reloads) ----
    {
      bool ok; CHECK8(ok, v0, g0, tick);
      while (!ok) { LOAD8(v0, g0, D0, T0); CHECK8(ok, v0, g0, tick); }
    }
    RESTAGE8(h0N, v0);   // double-buffered: no pre-barrier needed

    if (do1) {
      bool ok; CHECK8(ok, v1, g1, tick);
      while (!ok) { LOAD8(v1, g1, D1, T1); CHECK8(ok, v1, g1, tick); }
      RESTAGE8(h1N, v1);
    }

    if (xpf) {
      int r = tid >> 4, i0 = (tid & 15) * 8;
      bf16x8 v = cvt8(xr0, xr1);
      char* dst = smem + XOFF + ((t + 1) & 1) * XSZ;
      *(bf16x8*)(dst + ((r * 256 + i0 * 2) ^ ((r & 7) << 4))) = v;
    }
    __syncthreads();   // the single per-tick barrier
  }

  // ---------------- FC epilogue: out = h1(NT-1) @ fcW^T + fcb ----------------
  {
    // v1/g1 hold the speculative ingest of slab(1,1) tick NT+1 from the break tick
    u64*      DF = slabD(dat, 1, 1, g);
    unsigned* TF = slabT(tag, 1, 1, g);
    u64 vf[8]; unsigned gf[8];
#pragma unroll
    for (int i_ = 0; i_ < 8; ++i_) { vf[i_] = 0; gf[i_] = 0; }
    bool ok = false;
    // reuse nothing (v1/g1 scoped inside loop) — fresh validated ingest:
    LOAD8(vf, gf, DF, TF);
    CHECK8(ok, vf, gf, (unsigned)(NT + 1));
    while (!ok) { LOAD8(vf, gf, DF, TF); CHECK8(ok, vf, gf, (unsigned)(NT + 1)); }
    char* hF = smem + H1OFF + HSZ;  // buf1: last read at t=NT-1, free now
    RESTAGE8(hF, vf);
    __syncthreads();
  }
  if (wv == 0) {
    const char* hF = smem + H1OFF + HSZ;
    f32x4 acc = {0.f,0.f,0.f,0.f};
#pragma unroll
    for (int kt = 0; kt < 16; ++kt) {
      bf16x8 b = HFRAG(hF, kt);
      bf16x8 a = loadWfrag(fcW, NH, j * 16 + lr, kt * 32 + lq * 8);
      acc = MFMA16(a, b, acc);
    }
    f32x4 fb = *(const f32x4*)(fcb + j * 16 + lq * 4);
    *(f32x4*)(out + (size_t)(row0 + lr) * NO + j * 16 + lq * 4) = acc + fb;
  }
#undef RESTAGE8
#undef CHECK8
#undef LOAD8
#undef HFRAG
}

extern "C" void kernel_launch(void* const* d_in, const int* in_sizes, int n_in,
                              void* d_out, int out_size, void* d_ws, size_t ws_size,
                              hipStream_t stream)
{
  const float* x    = (const float*)d_in[0];
  const float* hid  = (const float*)d_in[1];
  const float* Wih0 = (const float*)d_in[2];
  const float* bih0 = (const float*)d_in[3];
  const float* Whh0 = (const float*)d_in[4];
  const float* bhh0 = (const float*)d_in[5];
  const float* Wih1 = (const float*)d_in[6];
  const float* bih1 = (const float*)d_in[7];
  const float* Whh1 = (const float*)d_in[8];
  const float* bhh1 = (const float*)d_in[9];
  const float* fcW  = (const float*)d_in[10];
  const float* fcb  = (const float*)d_in[11];
  float* out = (float*)d_out;

  u64* ex = (u64*)d_ws;   // [0,1MB) u64 data slabs; [1MB,1.5MB) u32 tags

  // zero data+tags every launch (replay safety: no stale tag can validate)
  (void)hipMemsetAsync(d_ws, 0, (size_t)(1024 + 512) * 1024, stream);

  hipLaunchKernelGGL(rnn_persistent, dim3(NGRP * BPG), dim3(256), 0, stream,
                     x, hid, Wih0, bih0, Whh0, bhh0, Wih1, bih1, Whh1, bhh1,
                     fcW, fcb, out, ex);
}

// Round 10
// 2127.715 us; speedup vs baseline: 2.2646x; 2.2646x over previous
//
#include <hip/hip_runtime.h>

// ---------------- problem constants ----------------
#define NB 256     // batch
#define NT 512     // seq len
#define NI 128     // input size
#define NH 512     // hidden
#define NO 128     // output size
#define NGRP 16    // batch groups
#define RPG 16     // rows (batch) per group
#define BPG 8      // blocks per group (each owns 64 cols)

typedef __attribute__((ext_vector_type(8))) __bf16 bf16x8;
typedef __attribute__((ext_vector_type(4))) float  f32x4;
typedef unsigned long long u64;

#define MFMA16(a,b,c) __builtin_amdgcn_mfma_f32_16x16x32_bf16((a),(b),(c),0,0,0)

// ---------------- LDS layout (x, h0, h1 double-buffered) ----------------
#define XSZ   (RPG*NI*2)            // 4096
#define HSZ   (RPG*NH*2)            // 16384
#define XOFF  0
#define H0OFF (2*XSZ)               // 8192
#define H1OFF (H0OFF + 2*HSZ)       // 40960
#define SMEM_BYTES (H1OFF + 2*HSZ)  // 73728

// ---------------- exchange: u64 data slabs + u32 tags ----------------
// slab layout: idx = quad*16 + row  (quad 0..127 = col/4, row 0..15)
//  -> publisher wave writes 64 CONSECUTIVE u64 (coalesced 512B)
//  -> reader thread t reads u64 [8t, 8t+8) (wide 64B contiguous)
#define SLABU   2048                // u64 per (layer,parity,group) slab = 16KB
#define DATAU   (4*NGRP*SLABU)      // 131072 u64 = 1MB

union U64x8 { uint4 q[4]; u64 v[8]; };
union U32x8 { uint4 q[2]; unsigned g[8]; };

__device__ __forceinline__ float fast_tanh(float x){
  x = fminf(15.f, fmaxf(-15.f, x));
  float e = __expf(2.f * x);
  return 1.f - 2.f / (e + 1.f);
}

__device__ __forceinline__ bf16x8 cvt8(float4 a, float4 b){
  bf16x8 r;
  r[0]=(__bf16)a.x; r[1]=(__bf16)a.y; r[2]=(__bf16)a.z; r[3]=(__bf16)a.w;
  r[4]=(__bf16)b.x; r[5]=(__bf16)b.y; r[6]=(__bf16)b.z; r[7]=(__bf16)b.w;
  return r;
}

__device__ __forceinline__ bf16x8 loadWfrag(const float* __restrict__ W, int ldk, int row, int k0){
  const float4* p = (const float4*)(W + (size_t)row * ldk + k0);
  return cvt8(p[0], p[1]);
}

// proven medium: relaxed agent-scope atomics (retry path + publish)
__device__ __forceinline__ void st_u64(u64* p, u64 v){
  __hip_atomic_store(p, v, __ATOMIC_RELAXED, __HIP_MEMORY_SCOPE_AGENT);
}
__device__ __forceinline__ u64 ld_u64(const u64* p){
  return __hip_atomic_load(p, __ATOMIC_RELAXED, __HIP_MEMORY_SCOPE_AGENT);
}
__device__ __forceinline__ void st_u32(unsigned* p, unsigned v){
  __hip_atomic_store(p, v, __ATOMIC_RELAXED, __HIP_MEMORY_SCOPE_AGENT);
}
__device__ __forceinline__ unsigned ld_u32(const unsigned* p){
  return __hip_atomic_load(p, __ATOMIC_RELAXED, __HIP_MEMORY_SCOPE_AGENT);
}

// wide first-pass load: non-atomic, full cache bypass; checksum validates
__device__ __forceinline__ uint4 wld16(const void* p){
  uint4 r;
  asm volatile("global_load_dwordx4 %0, %1, off sc0 sc1" : "=&v"(r) : "v"(p) : "memory");
  return r;
}
// rule #18 fence: drain all VMEM, then stop the scheduler moving uses above it
__device__ __forceinline__ void wait_all(){
  asm volatile("s_waitcnt vmcnt(0)" ::: "memory");
  __builtin_amdgcn_sched_barrier(0);
}

__device__ __forceinline__ u64 pack4bf(f32x4 v){
  union { __bf16 h[4]; u64 u; } un;
  un.h[0]=(__bf16)v[0]; un.h[1]=(__bf16)v[1]; un.h[2]=(__bf16)v[2]; un.h[3]=(__bf16)v[3];
  return un.u;
}

// checksum tag: staleness + tearing detection; mismatch -> retry
__device__ __forceinline__ unsigned cksum(unsigned tick, u64 d){
  return tick + (unsigned)d + (unsigned)(d >> 32);
}

__device__ __forceinline__ u64* slabD(u64* b, int l, int p, int g){
  return b + ((size_t)(((l << 1) | p) * NGRP + g)) * SLABU;
}
__device__ __forceinline__ unsigned* slabT(unsigned* b, int l, int p, int g){
  return b + ((size_t)(((l << 1) | p) * NGRP + g)) * SLABU;
}

__global__ __launch_bounds__(256, 1)
void rnn_persistent(const float* __restrict__ x,
                    const float* __restrict__ hid,
                    const float* __restrict__ Wih0, const float* __restrict__ bih0,
                    const float* __restrict__ Whh0, const float* __restrict__ bhh0,
                    const float* __restrict__ Wih1, const float* __restrict__ bih1,
                    const float* __restrict__ Whh1, const float* __restrict__ bhh1,
                    const float* __restrict__ fcW,  const float* __restrict__ fcb,
                    float* __restrict__ out,
                    u64* __restrict__ ex)           // data; u32 tags at ex+DATAU
{
  __shared__ __align__(16) char smem[SMEM_BYTES];

  const int tid  = threadIdx.x;
  const int lane = tid & 63;
  const int wv   = tid >> 6;
  const int lr   = lane & 15;
  const int lq   = lane >> 4;

  const int bq  = blockIdx.x;
  const int j   = (bq >> 3) & 7;            // block-in-group: cols [j*64, j*64+64)
  const int g   = (bq & 7) + 8 * (bq >> 6); // group 0..15
  const int cb  = j * 64 + wv * 16;
  const int row0 = g * RPG;
  const int idxp = j * 256 + wv * 64 + lane; // publish index: quad*16+row, coalesced

  u64* const dat = ex;
  unsigned* const tag = (unsigned*)(ex + DATAU);

  // ---------------- weights -> registers (MFMA A operands) ----------------
  bf16x8 wih0[4], whh0[16], wih1[16], whh1[16];
#pragma unroll
  for (int kt = 0; kt < 4;  ++kt) wih0[kt] = loadWfrag(Wih0, NI, cb + lr, kt*32 + lq*8);
#pragma unroll
  for (int kt = 0; kt < 16; ++kt) whh0[kt] = loadWfrag(Whh0, NH, cb + lr, kt*32 + lq*8);
#pragma unroll
  for (int kt = 0; kt < 16; ++kt) wih1[kt] = loadWfrag(Wih1, NH, cb + lr, kt*32 + lq*8);
#pragma unroll
  for (int kt = 0; kt < 16; ++kt) whh1[kt] = loadWfrag(Whh1, NH, cb + lr, kt*32 + lq*8);

  const f32x4 bias0 = *(const f32x4*)(bih0 + cb + lq*4) + *(const f32x4*)(bhh0 + cb + lq*4);
  const f32x4 bias1 = *(const f32x4*)(bih1 + cb + lq*4) + *(const f32x4*)(bhh1 + cb + lq*4);

  // ---------------- prologue staging ----------------
  { // x_0 -> X buf0
    int r = tid >> 4, i0 = (tid & 15) * 8;
    const float4* xp = (const float4*)(x + ((size_t)(row0 + r) * NT + 0) * NI + i0);
    bf16x8 v = cvt8(xp[0], xp[1]);
    int o = r * 256 + i0 * 2;
    *(bf16x8*)(smem + XOFF + (o ^ ((r & 7) << 4))) = v;
  }
#pragma unroll
  for (int it = 0; it < 4; ++it) { // hidden[0] -> h0 buf0 ; hidden[1] -> h1 buf1
    int e = it * 2048 + tid * 8;
    int r = e >> 9, c = e & 511;
    int o = r * 1024 + c * 2;
    const float4* hp0 = (const float4*)(hid + (size_t)(row0 + r) * NH + c);
    *(bf16x8*)(smem + H0OFF + (o ^ ((r & 7) << 4))) = cvt8(hp0[0], hp0[1]);
    const float4* hp1 = (const float4*)(hid + (size_t)NB * NH + (size_t)(row0 + r) * NH + c);
    *(bf16x8*)(smem + H1OFF + HSZ + (o ^ ((r & 7) << 4))) = cvt8(hp1[0], hp1[1]);
  }
  __syncthreads();

#define HFRAG(base, kt) (*(const bf16x8*)((base) + lr * 1024 + (((kt) * 64 + lq * 16) ^ ((lr & 7) << 4))))

// retry path: proven 8B atomic loads, per-thread contiguous [8t, 8t+8)
#define LOAD8(V, G, D, T)                                                              \
  { _Pragma("unroll") for (int i_ = 0; i_ < 8; ++i_) V[i_] = ld_u64((D) + tid*8 + i_); \
    _Pragma("unroll") for (int i_ = 0; i_ < 8; ++i_) G[i_] = ld_u32((T) + tid*8 + i_); }

#define CHECK8(OK, V, G, TICK)                                                         \
  { OK = true;                                                                         \
    _Pragma("unroll") for (int i_ = 0; i_ < 8; ++i_)                                   \
      OK &= (G[i_] == cksum((TICK), V[i_])); }

// slab idx n = 8*tid+i : quad = tid>>1, row = (tid&1)*8 + i  (row&7 == i)
#define RESTAGE8(BASE, V)                                                              \
  { _Pragma("unroll") for (int i_ = 0; i_ < 8; ++i_) {                                 \
      int o_ = ((tid & 1) * 8 + i_) * 1024 + (tid >> 1) * 8;                           \
      *(u64*)((BASE) + (o_ ^ (i_ << 4))) = V[i_]; } }

#define UNPACK8(V, G, A0, A1, A2, A3, T0, T1)                                          \
  { U64x8 U_; U_.q[0]=(A0); U_.q[1]=(A1); U_.q[2]=(A2); U_.q[3]=(A3);                  \
    U32x8 G_; G_.q[0]=(T0); G_.q[1]=(T1);                                              \
    _Pragma("unroll") for (int i_ = 0; i_ < 8; ++i_) { V[i_]=U_.v[i_]; G[i_]=G_.g[i_]; } }

  // tick t: compute h0(t) [t<NT] and h1(t-1) [t>0]; one barrier per tick
  for (int t = 0; t <= NT; ++t) {
    const char* xA  = smem + XOFF  + (t & 1) * XSZ;
    const char* h0A = smem + H0OFF + (t & 1) * HSZ;
    const char* h1A = smem + H1OFF + (t & 1) * HSZ;
    char* h0N = smem + H0OFF + ((t + 1) & 1) * HSZ;
    char* h1N = smem + H1OFF + ((t + 1) & 1) * HSZ;
    const bool do0 = (t < NT), do1 = (t > 0);
    const unsigned tick = (unsigned)(t + 1);

    u64*      D0 = slabD(dat, 0, t & 1, g);
    unsigned* T0 = slabT(tag, 0, t & 1, g);
    u64*      D1 = slabD(dat, 1, (t + 1) & 1, g);
    unsigned* T1 = slabT(tag, 1, (t + 1) & 1, g);

    // ---- layer 0 compute + publish (coalesced) ----
    if (do0) {
      f32x4 a0={0.f,0.f,0.f,0.f}, a1={0.f,0.f,0.f,0.f};
#pragma unroll
      for (int kt = 0; kt < 4; ++kt) {
        bf16x8 a = *(const bf16x8*)(xA + lr * 256 + ((kt * 64 + lq * 16) ^ ((lr & 7) << 4)));
        a0 = MFMA16(wih0[kt], a, a0);
      }
#pragma unroll
      for (int kt = 0; kt < 16; ++kt) {
        bf16x8 a = HFRAG(h0A, kt);
        if (kt & 1) a1 = MFMA16(whh0[kt], a, a1); else a0 = MFMA16(whh0[kt], a, a0);
      }
      f32x4 s = a0 + a1 + bias0;
      f32x4 h; h[0]=fast_tanh(s[0]); h[1]=fast_tanh(s[1]); h[2]=fast_tanh(s[2]); h[3]=fast_tanh(s[3]);
      if (t == NT - 1)
        *(f32x4*)(out + NB * NO + (size_t)(row0 + lr) * NH + cb + lq * 4) = h;  // new_hidden[0]
      u64 d = pack4bf(h);
      st_u64(D0 + idxp, d);
      st_u32(T0 + idxp, cksum(tick, d));
    }

    // ---- layer 1 compute + publish ----
    if (do1) {
      f32x4 c0={0.f,0.f,0.f,0.f}, c1={0.f,0.f,0.f,0.f};
#pragma unroll
      for (int kt = 0; kt < 16; ++kt) {
        bf16x8 a = HFRAG(h0A, kt);   // h0(t-1)
        if (kt & 1) c1 = MFMA16(wih1[kt], a, c1); else c0 = MFMA16(wih1[kt], a, c0);
      }
#pragma unroll
      for (int kt = 0; kt < 16; ++kt) {
        bf16x8 a = HFRAG(h1A, kt);   // h1(t-2)
        if (kt & 1) c1 = MFMA16(whh1[kt], a, c1); else c0 = MFMA16(whh1[kt], a, c0);
      }
      f32x4 s = c0 + c1 + bias1;
      f32x4 h; h[0]=fast_tanh(s[0]); h[1]=fast_tanh(s[1]); h[2]=fast_tanh(s[2]); h[3]=fast_tanh(s[3]);
      if (t == NT)
        *(f32x4*)(out + NB * NO + (size_t)NB * NH + (size_t)(row0 + lr) * NH + cb + lq * 4) = h;  // new_hidden[1]
      u64 d = pack4bf(h);
      st_u64(D1 + idxp, d);
      st_u32(T1 + idxp, cksum(tick, d));
    }
    if (t == NT) break;

    // x(t+1) prefetch to registers (drains together with the wide loads)
    float4 xr0, xr1;
    const bool xpf = (t + 1 < NT);
    if (xpf) {
      int r = tid >> 4, i0 = (tid & 15) * 8;
      const float4* xp = (const float4*)(x + ((size_t)(row0 + r) * NT + (t + 1)) * NI + i0);
      xr0 = xp[0]; xr1 = xp[1];
    }

    // ---- wide ingest: both slabs issued back-to-back, ONE drain ----
    uint4 da0,da1,da2,da3, ta0,ta1, db0,db1,db2,db3, tb0,tb1;
    {
      const char* p0 = (const char*)D0 + (size_t)tid * 64;
      const char* q0 = (const char*)T0 + (size_t)tid * 32;
      da0 = wld16(p0);      da1 = wld16(p0 + 16);
      da2 = wld16(p0 + 32); da3 = wld16(p0 + 48);
      ta0 = wld16(q0);      ta1 = wld16(q0 + 16);
      const char* p1 = (const char*)D1 + (size_t)tid * 64;
      const char* q1 = (const char*)T1 + (size_t)tid * 32;
      db0 = wld16(p1);      db1 = wld16(p1 + 16);
      db2 = wld16(p1 + 32); db3 = wld16(p1 + 48);
      tb0 = wld16(q1);      tb1 = wld16(q1 + 16);
    }
    wait_all();   // vmcnt(0) + sched_barrier: everything has landed, no hoisting

    u64 v0[8]; unsigned g0[8];
    UNPACK8(v0, g0, da0, da1, da2, da3, ta0, ta1);
    {
      bool ok; CHECK8(ok, v0, g0, tick);
      while (!ok) { LOAD8(v0, g0, D0, T0); CHECK8(ok, v0, g0, tick); }  // proven-atomic retry
    }
    RESTAGE8(h0N, v0);

    if (do1) {
      u64 v1[8]; unsigned g1[8];
      UNPACK8(v1, g1, db0, db1, db2, db3, tb0, tb1);
      bool ok; CHECK8(ok, v1, g1, tick);
      while (!ok) { LOAD8(v1, g1, D1, T1); CHECK8(ok, v1, g1, tick); }
      RESTAGE8(h1N, v1);
    }

    if (xpf) {
      int r = tid >> 4, i0 = (tid & 15) * 8;
      bf16x8 v = cvt8(xr0, xr1);
      char* dst = smem + XOFF + ((t + 1) & 1) * XSZ;
      *(bf16x8*)(dst + ((r * 256 + i0 * 2) ^ ((r & 7) << 4))) = v;
    }
    __syncthreads();   // the single per-tick barrier
  }

  // ---------------- FC epilogue: out = h1(NT-1) @ fcW^T + fcb ----------------
  {
    u64*      DF = slabD(dat, 1, 1, g);   // h1(NT-1): layer 1, parity 1, tick NT+1
    unsigned* TF = slabT(tag, 1, 1, g);
    uint4 da0,da1,da2,da3, ta0,ta1;
    const char* p0 = (const char*)DF + (size_t)tid * 64;
    const char* q0 = (const char*)TF + (size_t)tid * 32;
    da0 = wld16(p0);      da1 = wld16(p0 + 16);
    da2 = wld16(p0 + 32); da3 = wld16(p0 + 48);
    ta0 = wld16(q0);      ta1 = wld16(q0 + 16);
    wait_all();
    u64 vf[8]; unsigned gf[8];
    UNPACK8(vf, gf, da0, da1, da2, da3, ta0, ta1);
    bool ok; CHECK8(ok, vf, gf, (unsigned)(NT + 1));
    while (!ok) { LOAD8(vf, gf, DF, TF); CHECK8(ok, vf, gf, (unsigned)(NT + 1)); }
    char* hF = smem + H1OFF + HSZ;  // buf1: not read at t==NT, free
    RESTAGE8(hF, vf);
    __syncthreads();
  }
  if (wv == 0) {
    const char* hF = smem + H1OFF + HSZ;
    f32x4 acc = {0.f,0.f,0.f,0.f};
#pragma unroll
    for (int kt = 0; kt < 16; ++kt) {
      bf16x8 b = HFRAG(hF, kt);
      bf16x8 a = loadWfrag(fcW, NH, j * 16 + lr, kt * 32 + lq * 8);
      acc = MFMA16(a, b, acc);
    }
    f32x4 fb = *(const f32x4*)(fcb + j * 16 + lq * 4);
    *(f32x4*)(out + (size_t)(row0 + lr) * NO + j * 16 + lq * 4) = acc + fb;
  }
#undef UNPACK8
#undef RESTAGE8
#undef CHECK8
#undef LOAD8
#undef HFRAG
}

extern "C" void kernel_launch(void* const* d_in, const int* in_sizes, int n_in,
                              void* d_out, int out_size, void* d_ws, size_t ws_size,
                              hipStream_t stream)
{
  const float* x    = (const float*)d_in[0];
  const float* hid  = (const float*)d_in[1];
  const float* Wih0 = (const float*)d_in[2];
  const float* bih0 = (const float*)d_in[3];
  const float* Whh0 = (const float*)d_in[4];
  const float* bhh0 = (const float*)d_in[5];
  const float* Wih1 = (const float*)d_in[6];
  const float* bih1 = (const float*)d_in[7];
  const float* Whh1 = (const float*)d_in[8];
  const float* bhh1 = (const float*)d_in[9];
  const float* fcW  = (const float*)d_in[10];
  const float* fcb  = (const float*)d_in[11];
  float* out = (float*)d_out;

  u64* ex = (u64*)d_ws;   // [0,1MB) u64 data slabs; [1MB,1.5MB) u32 tags

  // zero data+tags every launch (replay safety: no stale tag can validate)
  (void)hipMemsetAsync(d_ws, 0, (size_t)(1024 + 512) * 1024, stream);

  hipLaunchKernelGGL(rnn_persistent, dim3(NGRP * BPG), dim3(256), 0, stream,
                     x, hid, Wih0, bih0, Whh0, bhh0, Wih1, bih1, Whh1, bhh1,
                     fcW, fcb, out, ex);
}

// Round 11
// 1885.140 us; speedup vs baseline: 2.5560x; 1.1287x over previous
//
#include <hip/hip_runtime.h>

// ---------------- problem constants ----------------
#define NB 256     // batch
#define NT 512     // seq len
#define NI 128     // input size
#define NH 512     // hidden
#define NO 128     // output size
#define NGRP 16    // batch groups
#define RPG 16     // rows (batch) per group
#define BPG 8      // blocks per group (each owns 64 cols)

typedef __attribute__((ext_vector_type(8))) __bf16 bf16x8;
typedef __attribute__((ext_vector_type(4))) float  f32x4;
typedef unsigned long long u64;

#define MFMA16(a,b,c) __builtin_amdgcn_mfma_f32_16x16x32_bf16((a),(b),(c),0,0,0)

// ---------------- LDS layout (x, h0, h1 double-buffered) ----------------
#define XSZ   (RPG*NI*2)            // 4096
#define HSZ   (RPG*NH*2)            // 16384
#define XOFF  0
#define H0OFF (2*XSZ)               // 8192
#define H1OFF (H0OFF + 2*HSZ)       // 40960
#define SMEM_BYTES (H1OFF + 2*HSZ)  // 73728

// ---------------- exchange: u64 data slabs + u32 tags, 4-parity rotation ----
// slab layout: idx = quad*16 + row  (publisher wave writes 64 consecutive u64)
// 4 parities: address reuse gap = 4 ticks (> max inter-block skew ~2) so
// cacheable first-pass loads almost never see a surviving stale line; the
// checksum + sc1 retry makes any survivor harmless.
#define SLABU   2048                // u64 per (layer,parity,group) slab = 16KB
#define DATAU   (8*NGRP*SLABU)      // 262144 u64 = 2MB (2 layers x 4 parities)

union U64x8 { uint4 q[4]; u64 v[8]; };
union U32x8 { uint4 q[2]; unsigned g[8]; };

__device__ __forceinline__ float fast_tanh(float x){
  x = fminf(15.f, fmaxf(-15.f, x));
  float e = __expf(2.f * x);
  return 1.f - 2.f / (e + 1.f);
}

__device__ __forceinline__ bf16x8 cvt8(float4 a, float4 b){
  bf16x8 r;
  r[0]=(__bf16)a.x; r[1]=(__bf16)a.y; r[2]=(__bf16)a.z; r[3]=(__bf16)a.w;
  r[4]=(__bf16)b.x; r[5]=(__bf16)b.y; r[6]=(__bf16)b.z; r[7]=(__bf16)b.w;
  return r;
}

__device__ __forceinline__ bf16x8 loadWfrag(const float* __restrict__ W, int ldk, int row, int k0){
  const float4* p = (const float4*)(W + (size_t)row * ldk + k0);
  return cvt8(p[0], p[1]);
}

// proven medium: relaxed agent-scope atomics (publish + retry fallback)
__device__ __forceinline__ void st_u64(u64* p, u64 v){
  __hip_atomic_store(p, v, __ATOMIC_RELAXED, __HIP_MEMORY_SCOPE_AGENT);
}
__device__ __forceinline__ u64 ld_u64(const u64* p){
  return __hip_atomic_load(p, __ATOMIC_RELAXED, __HIP_MEMORY_SCOPE_AGENT);
}
__device__ __forceinline__ void st_u32(unsigned* p, unsigned v){
  __hip_atomic_store(p, v, __ATOMIC_RELAXED, __HIP_MEMORY_SCOPE_AGENT);
}
__device__ __forceinline__ unsigned ld_u32(const unsigned* p){
  return __hip_atomic_load(p, __ATOMIC_RELAXED, __HIP_MEMORY_SCOPE_AGENT);
}

__device__ __forceinline__ u64 pack4bf(f32x4 v){
  union { __bf16 h[4]; u64 u; } un;
  un.h[0]=(__bf16)v[0]; un.h[1]=(__bf16)v[1]; un.h[2]=(__bf16)v[2]; un.h[3]=(__bf16)v[3];
  return un.u;
}

// checksum tag: staleness + tearing detection; mismatch -> sc1 retry
__device__ __forceinline__ unsigned cksum(unsigned tick, u64 d){
  return tick + (unsigned)d + (unsigned)(d >> 32);
}

__device__ __forceinline__ u64* slabD(u64* b, int l, int p, int g){
  return b + ((size_t)(((l << 2) | p) * NGRP + g)) * SLABU;
}
__device__ __forceinline__ unsigned* slabT(unsigned* b, int l, int p, int g){
  return b + ((size_t)(((l << 2) | p) * NGRP + g)) * SLABU;
}

__global__ __launch_bounds__(256, 1)
void rnn_persistent(const float* __restrict__ x,
                    const float* __restrict__ hid,
                    const float* __restrict__ Wih0, const float* __restrict__ bih0,
                    const float* __restrict__ Whh0, const float* __restrict__ bhh0,
                    const float* __restrict__ Wih1, const float* __restrict__ bih1,
                    const float* __restrict__ Whh1, const float* __restrict__ bhh1,
                    const float* __restrict__ fcW,  const float* __restrict__ fcb,
                    float* __restrict__ out,
                    u64* __restrict__ ex)           // data; u32 tags at ex+DATAU
{
  __shared__ __align__(16) char smem[SMEM_BYTES];

  const int tid  = threadIdx.x;
  const int lane = tid & 63;
  const int wv   = tid >> 6;
  const int lr   = lane & 15;
  const int lq   = lane >> 4;

  const int bq  = blockIdx.x;
  const int j   = (bq >> 3) & 7;            // block-in-group: cols [j*64, j*64+64)
  const int g   = (bq & 7) + 8 * (bq >> 6); // group 0..15
  const int cb  = j * 64 + wv * 16;
  const int row0 = g * RPG;
  const int idxp = j * 256 + wv * 64 + lane; // publish index: quad*16+row, coalesced

  u64* const dat = ex;
  unsigned* const tag = (unsigned*)(ex + DATAU);

  // ---------------- weights -> registers (MFMA A operands) ----------------
  bf16x8 wih0[4], whh0[16], wih1[16], whh1[16];
#pragma unroll
  for (int kt = 0; kt < 4;  ++kt) wih0[kt] = loadWfrag(Wih0, NI, cb + lr, kt*32 + lq*8);
#pragma unroll
  for (int kt = 0; kt < 16; ++kt) whh0[kt] = loadWfrag(Whh0, NH, cb + lr, kt*32 + lq*8);
#pragma unroll
  for (int kt = 0; kt < 16; ++kt) wih1[kt] = loadWfrag(Wih1, NH, cb + lr, kt*32 + lq*8);
#pragma unroll
  for (int kt = 0; kt < 16; ++kt) whh1[kt] = loadWfrag(Whh1, NH, cb + lr, kt*32 + lq*8);

  const f32x4 bias0 = *(const f32x4*)(bih0 + cb + lq*4) + *(const f32x4*)(bhh0 + cb + lq*4);
  const f32x4 bias1 = *(const f32x4*)(bih1 + cb + lq*4) + *(const f32x4*)(bhh1 + cb + lq*4);

  // ---------------- prologue staging ----------------
  { // x_0 -> X buf0
    int r = tid >> 4, i0 = (tid & 15) * 8;
    const float4* xp = (const float4*)(x + ((size_t)(row0 + r) * NT + 0) * NI + i0);
    bf16x8 v = cvt8(xp[0], xp[1]);
    int o = r * 256 + i0 * 2;
    *(bf16x8*)(smem + XOFF + (o ^ ((r & 7) << 4))) = v;
  }
#pragma unroll
  for (int it = 0; it < 4; ++it) { // hidden[0] -> h0 buf0 ; hidden[1] -> h1 buf1
    int e = it * 2048 + tid * 8;
    int r = e >> 9, c = e & 511;
    int o = r * 1024 + c * 2;
    const float4* hp0 = (const float4*)(hid + (size_t)(row0 + r) * NH + c);
    *(bf16x8*)(smem + H0OFF + (o ^ ((r & 7) << 4))) = cvt8(hp0[0], hp0[1]);
    const float4* hp1 = (const float4*)(hid + (size_t)NB * NH + (size_t)(row0 + r) * NH + c);
    *(bf16x8*)(smem + H1OFF + HSZ + (o ^ ((r & 7) << 4))) = cvt8(hp1[0], hp1[1]);
  }
  __syncthreads();

#define HFRAG(base, kt) (*(const bf16x8*)((base) + lr * 1024 + (((kt) * 64 + lq * 16) ^ ((lr & 7) << 4))))

// retry path: proven 8B sc1 atomic loads, per-thread contiguous [8t, 8t+8)
#define LOAD8(V, G, D, T)                                                              \
  { _Pragma("unroll") for (int i_ = 0; i_ < 8; ++i_) V[i_] = ld_u64((D) + tid*8 + i_); \
    _Pragma("unroll") for (int i_ = 0; i_ < 8; ++i_) G[i_] = ld_u32((T) + tid*8 + i_); }

#define CHECK8(OK, V, G, TICK)                                                         \
  { OK = true;                                                                         \
    _Pragma("unroll") for (int i_ = 0; i_ < 8; ++i_)                                   \
      OK &= (G[i_] == cksum((TICK), V[i_])); }

// fast first pass: plain cacheable wide loads (L2/L3-served); checksum validates
#define FASTLOAD8(V, G, D, T)                                                          \
  { const uint4* P_ = (const uint4*)((const char*)(D) + (size_t)tid * 64);             \
    const uint4* Q_ = (const uint4*)((const char*)(T) + (size_t)tid * 32);             \
    U64x8 U_; U_.q[0]=P_[0]; U_.q[1]=P_[1]; U_.q[2]=P_[2]; U_.q[3]=P_[3];              \
    U32x8 G_; G_.q[0]=Q_[0]; G_.q[1]=Q_[1];                                            \
    _Pragma("unroll") for (int i_ = 0; i_ < 8; ++i_) { V[i_]=U_.v[i_]; G[i_]=G_.g[i_]; } }

// slab idx n = 8*tid+i : quad = tid>>1, row = (tid&1)*8 + i  (row&7 == i)
#define RESTAGE8(BASE, V)                                                              \
  { _Pragma("unroll") for (int i_ = 0; i_ < 8; ++i_) {                                 \
      int o_ = ((tid & 1) * 8 + i_) * 1024 + (tid >> 1) * 8;                           \
      *(u64*)((BASE) + (o_ ^ (i_ << 4))) = V[i_]; } }

  // tick t: compute h0(t) [t<NT] and h1(t-1) [t>0]; one barrier per tick
  for (int t = 0; t <= NT; ++t) {
    const char* xA  = smem + XOFF  + (t & 1) * XSZ;
    const char* h0A = smem + H0OFF + (t & 1) * HSZ;
    const char* h1A = smem + H1OFF + (t & 1) * HSZ;
    char* h0N = smem + H0OFF + ((t + 1) & 1) * HSZ;
    char* h1N = smem + H1OFF + ((t + 1) & 1) * HSZ;
    const bool do0 = (t < NT), do1 = (t > 0);
    const unsigned tick = (unsigned)(t + 1);
    const int par = t & 3;                 // 4-parity slab rotation

    u64*      D0 = slabD(dat, 0, par, g);
    unsigned* T0 = slabT(tag, 0, par, g);
    u64*      D1 = slabD(dat, 1, par, g);
    unsigned* T1 = slabT(tag, 1, par, g);

    // ---- layer 0 compute + publish (sc1: proven visibility) ----
    if (do0) {
      f32x4 a0={0.f,0.f,0.f,0.f}, a1={0.f,0.f,0.f,0.f};
#pragma unroll
      for (int kt = 0; kt < 4; ++kt) {
        bf16x8 a = *(const bf16x8*)(xA + lr * 256 + ((kt * 64 + lq * 16) ^ ((lr & 7) << 4)));
        a0 = MFMA16(wih0[kt], a, a0);
      }
#pragma unroll
      for (int kt = 0; kt < 16; ++kt) {
        bf16x8 a = HFRAG(h0A, kt);
        if (kt & 1) a1 = MFMA16(whh0[kt], a, a1); else a0 = MFMA16(whh0[kt], a, a0);
      }
      f32x4 s = a0 + a1 + bias0;
      f32x4 h; h[0]=fast_tanh(s[0]); h[1]=fast_tanh(s[1]); h[2]=fast_tanh(s[2]); h[3]=fast_tanh(s[3]);
      if (t == NT - 1)
        *(f32x4*)(out + NB * NO + (size_t)(row0 + lr) * NH + cb + lq * 4) = h;  // new_hidden[0]
      u64 d = pack4bf(h);
      st_u64(D0 + idxp, d);
      st_u32(T0 + idxp, cksum(tick, d));
    }

    // ---- layer 1 compute + publish ----
    if (do1) {
      f32x4 c0={0.f,0.f,0.f,0.f}, c1={0.f,0.f,0.f,0.f};
#pragma unroll
      for (int kt = 0; kt < 16; ++kt) {
        bf16x8 a = HFRAG(h0A, kt);   // h0(t-1)
        if (kt & 1) c1 = MFMA16(wih1[kt], a, c1); else c0 = MFMA16(wih1[kt], a, c0);
      }
#pragma unroll
      for (int kt = 0; kt < 16; ++kt) {
        bf16x8 a = HFRAG(h1A, kt);   // h1(t-2)
        if (kt & 1) c1 = MFMA16(whh1[kt], a, c1); else c0 = MFMA16(whh1[kt], a, c0);
      }
      f32x4 s = c0 + c1 + bias1;
      f32x4 h; h[0]=fast_tanh(s[0]); h[1]=fast_tanh(s[1]); h[2]=fast_tanh(s[2]); h[3]=fast_tanh(s[3]);
      if (t == NT)
        *(f32x4*)(out + NB * NO + (size_t)NB * NH + (size_t)(row0 + lr) * NH + cb + lq * 4) = h;  // new_hidden[1]
      u64 d = pack4bf(h);
      st_u64(D1 + idxp, d);
      st_u32(T1 + idxp, cksum(tick, d));
    }
    if (t == NT) break;

    // x(t+1) prefetch to registers
    float4 xr0, xr1;
    const bool xpf = (t + 1 < NT);
    if (xpf) {
      int r = tid >> 4, i0 = (tid & 15) * 8;
      const float4* xp = (const float4*)(x + ((size_t)(row0 + r) * NT + (t + 1)) * NI + i0);
      xr0 = xp[0]; xr1 = xp[1];
    }

    // ---- ingest: cacheable first pass, checksum-gated; sc1 retry fallback ----
    {
      u64 v0[8]; unsigned g0[8];
      FASTLOAD8(v0, g0, D0, T0);
      bool ok; CHECK8(ok, v0, g0, tick);
      while (!ok) { LOAD8(v0, g0, D0, T0); CHECK8(ok, v0, g0, tick); }
      RESTAGE8(h0N, v0);
    }
    if (do1) {
      u64 v1[8]; unsigned g1[8];
      FASTLOAD8(v1, g1, D1, T1);
      bool ok; CHECK8(ok, v1, g1, tick);
      while (!ok) { LOAD8(v1, g1, D1, T1); CHECK8(ok, v1, g1, tick); }
      RESTAGE8(h1N, v1);
    }

    if (xpf) {
      int r = tid >> 4, i0 = (tid & 15) * 8;
      bf16x8 v = cvt8(xr0, xr1);
      char* dst = smem + XOFF + ((t + 1) & 1) * XSZ;
      *(bf16x8*)(dst + ((r * 256 + i0 * 2) ^ ((r & 7) << 4))) = v;
    }
    __syncthreads();   // the single per-tick barrier
  }

  // ---------------- FC epilogue: out = h1(NT-1) @ fcW^T + fcb ----------------
  {
    u64*      DF = slabD(dat, 1, NT & 3, g);   // h1(NT-1): published at tick NT
    unsigned* TF = slabT(tag, 1, NT & 3, g);
    u64 vf[8]; unsigned gf[8];
    FASTLOAD8(vf, gf, DF, TF);
    bool ok; CHECK8(ok, vf, gf, (unsigned)(NT + 1));
    while (!ok) { LOAD8(vf, gf, DF, TF); CHECK8(ok, vf, gf, (unsigned)(NT + 1)); }
    char* hF = smem + H1OFF + HSZ;  // buf1: not read at t==NT, free
    RESTAGE8(hF, vf);
    __syncthreads();
  }
  if (wv == 0) {
    const char* hF = smem + H1OFF + HSZ;
    f32x4 acc = {0.f,0.f,0.f,0.f};
#pragma unroll
    for (int kt = 0; kt < 16; ++kt) {
      bf16x8 b = HFRAG(hF, kt);
      bf16x8 a = loadWfrag(fcW, NH, j * 16 + lr, kt * 32 + lq * 8);
      acc = MFMA16(a, b, acc);
    }
    f32x4 fb = *(const f32x4*)(fcb + j * 16 + lq * 4);
    *(f32x4*)(out + (size_t)(row0 + lr) * NO + j * 16 + lq * 4) = acc + fb;
  }
#undef RESTAGE8
#undef FASTLOAD8
#undef CHECK8
#undef LOAD8
#undef HFRAG
}

extern "C" void kernel_launch(void* const* d_in, const int* in_sizes, int n_in,
                              void* d_out, int out_size, void* d_ws, size_t ws_size,
                              hipStream_t stream)
{
  const float* x    = (const float*)d_in[0];
  const float* hid  = (const float*)d_in[1];
  const float* Wih0 = (const float*)d_in[2];
  const float* bih0 = (const float*)d_in[3];
  const float* Whh0 = (const float*)d_in[4];
  const float* bhh0 = (const float*)d_in[5];
  const float* Wih1 = (const float*)d_in[6];
  const float* bih1 = (const float*)d_in[7];
  const float* Whh1 = (const float*)d_in[8];
  const float* bhh1 = (const float*)d_in[9];
  const float* fcW  = (const float*)d_in[10];
  const float* fcb  = (const float*)d_in[11];
  float* out = (float*)d_out;

  u64* ex = (u64*)d_ws;   // [0,2MB) u64 data slabs (2 layers x 4 parities); [2MB,3MB) u32 tags

  // zero data+tags every launch (replay safety: no stale tag can validate)
  (void)hipMemsetAsync(d_ws, 0, (size_t)3 * 1024 * 1024, stream);

  hipLaunchKernelGGL(rnn_persistent, dim3(NGRP * BPG), dim3(256), 0, stream,
                     x, hid, Wih0, bih0, Whh0, bhh0, Wih1, bih1, Whh1, bhh1,
                     fcW, fcb, out, ex);
}